// Round 1
// baseline (534.584 us; speedup 1.0000x reference)
//
#include <hip/hip_runtime.h>
#include <hip/hip_bf16.h>
#include <math.h>

// B=4, T=2048, C=1024, H=16, Dh=64.

typedef __attribute__((ext_vector_type(8))) short short8;   // 8 bf16 (4 VGPRs)
typedef __attribute__((ext_vector_type(4))) float f32x4;

__device__ __forceinline__ short f2bf(float f) {
    __hip_bfloat16 h = __float2bfloat16(f);
    return *reinterpret_cast<short*>(&h);
}
__device__ __forceinline__ float bf2f(short s) {
    __hip_bfloat16 h = *reinterpret_cast<__hip_bfloat16*>(&s);
    return __bfloat162float(h);
}

#define MFMA16(a, b, c) __builtin_amdgcn_mfma_f32_16x16x32_bf16((a), (b), (c), 0, 0, 0)

// async 16B global->LDS (lds dest: wave-uniform base + lane*16)
__device__ __forceinline__ void gload_lds16(const short* g, short* l) {
    __builtin_amdgcn_global_load_lds(
        (const __attribute__((address_space(1))) void*)g,
        (__attribute__((address_space(3))) void*)l, 16, 0, 0);
}

// ---------------------------------------------------------------------------
// Dtype sniff: fp32 inputs (flag=1) vs bf16 (flag=0).
// ---------------------------------------------------------------------------
__global__ void sniff_kernel(const unsigned int* __restrict__ xb,
                             unsigned int* __restrict__ flag)
{
    __shared__ int cnt;
    if (threadIdx.x == 0) cnt = 0;
    __syncthreads();
    int c = 0;
    for (int i = threadIdx.x; i < 4096; i += 256) {
        unsigned e = (xb[i] >> 7) & 0xFFu;
        if (e >= 96u && e <= 142u) ++c;
    }
    atomicAdd(&cnt, c);
    __syncthreads();
    if (threadIdx.x == 0) *flag = (cnt < 2048) ? 1u : 0u;
}

// ---------------------------------------------------------------------------
// Transpose + convert-to-bf16: out[c][r] = bf16(in[r][c]).
// ---------------------------------------------------------------------------
__global__ __launch_bounds__(256)
void transpose_cvt(const void* __restrict__ in, short* __restrict__ out,
                   int R, int C, const unsigned int* __restrict__ flagp)
{
    const bool f32in = (*flagp != 0u);
    __shared__ short tile[64][65];
    const int bx = blockIdx.x * 64;
    const int by = blockIdx.y * 64;
    const int tx = threadIdx.x & 63;
    const int ty = threadIdx.x >> 6;
#pragma unroll
    for (int i = 0; i < 64; i += 4) {
        size_t idx = (size_t)(by + ty + i) * C + bx + tx;
        tile[ty + i][tx] = f32in ? f2bf(((const float*)in)[idx])
                                 : ((const short*)in)[idx];
    }
    __syncthreads();
#pragma unroll
    for (int i = 0; i < 64; i += 4)
        out[(size_t)(bx + ty + i) * R + by + tx] = tile[tx][ty + i];
}

// ---------------------------------------------------------------------------
// GEMM: C = A[M][K] @ B (Bt[N][K] bf16) + bias.  128x128 tile, BK=32.
// Staging via global_load_lds width=16 into UNPADDED stride-32 LDS (m97).
// EPI=1 (QKV): scatter Q,K [BH][T][64], V transposed [BH][64][T].
// EPI=0 (proj): row-major out, dtype per flag.
// ---------------------------------------------------------------------------
template <int EPI>
__global__ __launch_bounds__(256)
void gemm_kernel(const void* __restrict__ A,
                 const short* __restrict__ Bt,
                 const void* __restrict__ bias,
                 void* __restrict__ O0,
                 short* __restrict__ O1,
                 short* __restrict__ O2,
                 int M, int N, int K,
                 const unsigned int* __restrict__ flagp)
{
    const bool f32io = (*flagp != 0u);
    __shared__ __align__(16) short ldsA[128 * 32];  // [m][k] stride 32, no pad
    __shared__ __align__(16) short ldsB[128 * 32];  // [n][k]

    const int tid = threadIdx.x;
    const int lane = tid & 63;
    const int wv = tid >> 6;
    const int wm = (wv & 1) * 64;
    const int wn = (wv >> 1) * 64;
    const int tile_m = blockIdx.y * 128;
    const int tile_n = blockIdx.x * 128;

    f32x4 acc[4][4];
#pragma unroll
    for (int i = 0; i < 4; ++i)
#pragma unroll
        for (int j = 0; j < 4; ++j) acc[i][j] = (f32x4){0.f, 0.f, 0.f, 0.f};

    const int ar = lane & 15;
    const int aq = (lane >> 4) * 8;
    const int lrow = lane >> 2;          // 0..15
    const int lcol = (lane & 3) << 3;    // 0,8,16,24

    for (int k0 = 0; k0 < K; k0 += 32) {
        if (EPI == 1 && f32io) {
#pragma unroll
            for (int p = 0; p < 2; ++p) {
                int idx = tid + p * 256;
                int row = idx >> 2;
                int col = (idx & 3) << 3;
                const float* Af = (const float*)A;
                const f32x4* fp = (const f32x4*)(Af + (size_t)(tile_m + row) * K + (k0 + col));
                f32x4 u0 = fp[0], u1 = fp[1];
                short8 v;
#pragma unroll
                for (int j = 0; j < 4; ++j) { v[j] = f2bf(u0[j]); v[j + 4] = f2bf(u1[j]); }
                *(short8*)(ldsA + row * 32 + col) = v;
            }
        } else {
            const short* Ag = (const short*)A;
#pragma unroll
            for (int p = 0; p < 2; ++p) {
                int c = wv * 2 + p;
                int row = c * 16 + lrow;
                gload_lds16(Ag + (size_t)(tile_m + row) * K + k0 + lcol, ldsA + c * 512);
            }
        }
#pragma unroll
        for (int p = 0; p < 2; ++p) {
            int c = wv * 2 + p;
            int row = c * 16 + lrow;
            gload_lds16(Bt + (size_t)(tile_n + row) * K + k0 + lcol, ldsB + c * 512);
        }
        __syncthreads();

        short8 af[4], bfr[4];
#pragma unroll
        for (int i = 0; i < 4; ++i)
            af[i] = *(const short8*)(ldsA + (wm + i * 16 + ar) * 32 + aq);
#pragma unroll
        for (int j = 0; j < 4; ++j)
            bfr[j] = *(const short8*)(ldsB + (wn + j * 16 + ar) * 32 + aq);
#pragma unroll
        for (int i = 0; i < 4; ++i)
#pragma unroll
            for (int j = 0; j < 4; ++j)
                acc[i][j] = MFMA16(af[i], bfr[j], acc[i][j]);
        __syncthreads();
    }

    const int colq = lane & 15;
    const int rowq = (lane >> 4) * 4;
#pragma unroll
    for (int j = 0; j < 4; ++j) {
        int gn = tile_n + wn + j * 16 + colq;
        float bv = f32io ? ((const float*)bias)[gn] : bf2f(((const short*)bias)[gn]);
#pragma unroll
        for (int i = 0; i < 4; ++i) {
#pragma unroll
            for (int r = 0; r < 4; ++r) {
                int gm = tile_m + wm + i * 16 + rowq + r;
                float val = acc[i][j][r] + bv;
                if (EPI == 0) {
                    if (f32io) ((float*)O0)[(size_t)gm * N + gn] = val;
                    else       ((short*)O0)[(size_t)gm * N + gn] = f2bf(val);
                } else {
                    short o = f2bf(val);
                    int which = gn >> 10;
                    int c = gn & 1023;
                    int h = c >> 6;
                    int d = c & 63;
                    int b = gm >> 11;
                    int t = gm & 2047;
                    size_t bh = (size_t)(b * 16 + h);
                    if (which == 0)      ((short*)O0)[(bh * 2048 + t) * 64 + d] = o;
                    else if (which == 1) O1[(bh * 2048 + t) * 64 + d] = o;
                    else                 O2[(bh * 64 + d) * 2048 + t] = o;  // V^T
                }
            }
        }
    }
}

// ---------------------------------------------------------------------------
// Flash attention, causal, fixed-base softmax (exact: |scores| << 88).
// Q,K: [BH][2048][64], Vt: [BH][64][2048] bf16.  Y: [B][T][C] bf16.
//
// R1 restructure (latency-bound fix):
//  - UN-PAIRED jobs: one wave = ONE 16-row q-tile.  8192 waves (was 4096)
//    -> 8 waves/SIMD, 2x latency hiding.  Load balance handled by block
//    scheduler (4096 blocks; the 2 waves of a block own adjacent tiles so
//    intra-block cost is matched).
//  - XCD-AWARE swizzle: fid&7 = XCD; each XCD owns 8 complete bh values,
//    their 64 blocks dispatched consecutively -> each bh's 512KB K/V stays
//    resident in ONE XCD's 4MB L2 instead of being replicated/thrashed
//    across all 8 (was 650MB HBM fetch vs ~67MB ideal).
//
// SOFTWARE PIPELINE per iteration: issue V(kt) loads first; QK on
// prefetched K; issue K(kt+1) loads; exp/mask/P-store (hides V+K latency);
// P LDS round-trip; PV on already-arrived V.  P stride 36 shorts ->
// conflict-free ds_write (quad bank offsets {0,8,16,24}).
// Block = 2 waves (128 thr); grid 4096.  No min-waves bound (spill risk);
// VGPR must stay <=64 for 8 waves/SIMD — check VGPR_Count next round.
// ---------------------------------------------------------------------------
__global__ __launch_bounds__(128)
void attn_kernel(const short* __restrict__ Q,
                 const short* __restrict__ Kp_,
                 const short* __restrict__ Vt,
                 short* __restrict__ Y)
{
    __shared__ __align__(16) short pbuf[2][16 * 36];  // per-wave P [16 q][32 k]

    const int tid = threadIdx.x;
    const int lane = tid & 63;
    const int wv = tid >> 6;                  // 0..1
    const int m16 = lane & 15;
    const int quad = lane >> 4;

    // XCD-aware decode: 4096 blocks; xcd = fid&7 (HW round-robin heuristic),
    // 8 bh per XCD (bh = xcd*8 + slot/64), 64 consecutive blocks per bh.
    const int fid = blockIdx.x;
    const int xcd = fid & 7;
    const int slot = fid >> 3;                // 0..511
    const int bh = (xcd << 3) | (slot >> 6);  // 0..63
    const int sub = slot & 63;                // 0..63
    const int t16 = sub * 2 + wv;             // 0..127: this wave's q-tile

    const int b = bh >> 4, h = bh & 15;
    const int qtile = t16 * 16;

    const short* Qp = Q   + (size_t)bh * 2048 * 64;
    const short* Kp = Kp_ + (size_t)bh * 2048 * 64;
    const short* Vp = Vt  + (size_t)bh * 64 * 2048;
    short* pw = pbuf[wv];

    const float c2 = 0.125f * 1.44269504088896f;  // scale * log2(e)

    short8 aq0 = *(const short8*)(Qp + (size_t)(qtile + m16) * 64 + quad * 8);
    short8 aq1 = *(const short8*)(Qp + (size_t)(qtile + m16) * 64 + 32 + quad * 8);

    f32x4 o[4];
#pragma unroll
    for (int dt = 0; dt < 4; ++dt) o[dt] = (f32x4){0.f, 0.f, 0.f, 0.f};
    float lrow[4] = {0.f, 0.f, 0.f, 0.f};

    const int nkt = (t16 >> 1) + 1;           // 32-key tiles

    // prefetch K(0): 32 keys x 64 dims as 2 c-subtiles x 2 k-chunks
    short8 bk0, bk1, bk2, bk3;
    {
        const short* K0 = Kp + (size_t)m16 * 64 + quad * 8;
        bk0 = *(const short8*)(K0);
        bk1 = *(const short8*)(K0 + 32);
        bk2 = *(const short8*)(K0 + 16 * 64);
        bk3 = *(const short8*)(K0 + 16 * 64 + 32);
    }

    for (int kt = 0; kt < nkt; ++kt) {
        const int kb = kt << 5;
        // V(kt) loads first — independent, latency hidden under QK+exp
        const short* V0 = Vp + (size_t)m16 * 2048 + kb + quad * 8;
        short8 bv0 = *(const short8*)(V0);
        short8 bv1 = *(const short8*)(V0 + (size_t)16 * 2048);
        short8 bv2 = *(const short8*)(V0 + (size_t)32 * 2048);
        short8 bv3 = *(const short8*)(V0 + (size_t)48 * 2048);

        // QK on prefetched K
        f32x4 s0 = (f32x4){0.f, 0.f, 0.f, 0.f};
        f32x4 s1 = (f32x4){0.f, 0.f, 0.f, 0.f};
        s0 = MFMA16(aq0, bk0, s0);
        s0 = MFMA16(aq1, bk1, s0);
        s1 = MFMA16(aq0, bk2, s1);
        s1 = MFMA16(aq1, bk3, s1);

        // prefetch K(kt+1) (clamped; latency hidden under exp section)
        {
            const int kbn = (kt + 1 < nkt) ? (kb + 32) : kb;
            const short* Kn = Kp + (size_t)(kbn + m16) * 64 + quad * 8;
            bk0 = *(const short8*)(Kn);
            bk1 = *(const short8*)(Kn + 32);
            bk2 = *(const short8*)(Kn + 16 * 64);
            bk3 = *(const short8*)(Kn + 16 * 64 + 32);
        }

        // exp + mask + P store (fixed-base softmax)
#pragma unroll
        for (int c = 0; c < 2; ++c) {
            const f32x4 sv = c ? s1 : s0;
            const int key = kb + c * 16 + m16;
            const bool needmask = (kb + c * 16 + 15 > qtile);
#pragma unroll
            for (int r = 0; r < 4; ++r) {
                float p = exp2f(sv[r] * c2);
                if (needmask && key > qtile + quad * 4 + r) p = 0.f;
                lrow[r] += p;
                pw[(quad * 4 + r) * 36 + c * 16 + m16] = f2bf(p);
            }
        }

        // P (C-layout) -> A-operand via per-wave LDS round-trip
        asm volatile("" ::: "memory");
        short8 ap = *(const short8*)(pw + m16 * 36 + quad * 8);
        asm volatile("" ::: "memory");

        // PV — V already arrived (issued at top of iteration)
        o[0] = MFMA16(ap, bv0, o[0]);
        o[1] = MFMA16(ap, bv1, o[1]);
        o[2] = MFMA16(ap, bv2, o[2]);
        o[3] = MFMA16(ap, bv3, o[3]);
    }

    float linv[4];
#pragma unroll
    for (int r = 0; r < 4; ++r) {
        float sm = lrow[r];
#pragma unroll
        for (int off = 1; off < 16; off <<= 1)
            sm += __shfl_xor(sm, off);
        linv[r] = 1.0f / sm;
    }
#pragma unroll
    for (int dt = 0; dt < 4; ++dt) {
#pragma unroll
        for (int r = 0; r < 4; ++r) {
            int row = qtile + quad * 4 + r;
            int col = h * 64 + dt * 16 + m16;
            Y[((size_t)(b * 2048 + row)) * 1024 + col] = f2bf(o[dt][r] * linv[r]);
        }
    }
}

// ---------------------------------------------------------------------------
extern "C" void kernel_launch(void* const* d_in, const int* in_sizes, int n_in,
                              void* d_out, int out_size, void* d_ws, size_t ws_size,
                              hipStream_t stream)
{
    const void* x      = d_in[0];
    const void* w_attn = d_in[1];
    const void* b_attn = d_in[2];
    const void* w_proj = d_in[3];
    const void* b_proj = d_in[4];

    char* ws = (char*)d_ws;
    unsigned int* flag = (unsigned int*)(ws + 0);
    short* Wta = (short*)(ws + 256);
    short* Wtp = (short*)(ws + 6291712);
    short* Qb  = (short*)(ws + 8388864);
    short* Kb  = (short*)(ws + 25166080);
    short* Vtb = (short*)(ws + 41943296);
    short* Yb  = (short*)(ws + 58720512);

    sniff_kernel<<<1, 256, 0, stream>>>((const unsigned int*)x, flag);
    transpose_cvt<<<dim3(48, 16), 256, 0, stream>>>(w_attn, Wta, 1024, 3072, flag);
    transpose_cvt<<<dim3(16, 16), 256, 0, stream>>>(w_proj, Wtp, 1024, 1024, flag);
    gemm_kernel<1><<<dim3(24, 64), 256, 0, stream>>>(x, Wta, b_attn, Qb, Kb, Vtb,
                                                     8192, 3072, 1024, flag);
    attn_kernel<<<dim3(4096), 128, 0, stream>>>(Qb, Kb, Vtb, Yb);
    gemm_kernel<0><<<dim3(8, 64), 256, 0, stream>>>(Yb, Wtp, b_proj, d_out, nullptr, nullptr,
                                                    8192, 1024, 1024, flag);
}

// Round 2
// 508.303 us; speedup vs baseline: 1.0517x; 1.0517x over previous
//
#include <hip/hip_runtime.h>
#include <hip/hip_bf16.h>
#include <math.h>

// B=4, T=2048, C=1024, H=16, Dh=64.

typedef __attribute__((ext_vector_type(8))) short short8;   // 8 bf16 (4 VGPRs)
typedef __attribute__((ext_vector_type(4))) float f32x4;

__device__ __forceinline__ short f2bf(float f) {
    __hip_bfloat16 h = __float2bfloat16(f);
    return *reinterpret_cast<short*>(&h);
}
__device__ __forceinline__ float bf2f(short s) {
    __hip_bfloat16 h = *reinterpret_cast<__hip_bfloat16*>(&s);
    return __bfloat162float(h);
}

#define MFMA16(a, b, c) __builtin_amdgcn_mfma_f32_16x16x32_bf16((a), (b), (c), 0, 0, 0)

// async 16B global->LDS (lds dest: wave-uniform base + lane*16)
__device__ __forceinline__ void gload_lds16(const short* g, short* l) {
    __builtin_amdgcn_global_load_lds(
        (const __attribute__((address_space(1))) void*)g,
        (__attribute__((address_space(3))) void*)l, 16, 0, 0);
}

// ---------------------------------------------------------------------------
// Dtype sniff: fp32 inputs (flag=1) vs bf16 (flag=0).
// ---------------------------------------------------------------------------
__global__ void sniff_kernel(const unsigned int* __restrict__ xb,
                             unsigned int* __restrict__ flag)
{
    __shared__ int cnt;
    if (threadIdx.x == 0) cnt = 0;
    __syncthreads();
    int c = 0;
    for (int i = threadIdx.x; i < 4096; i += 256) {
        unsigned e = (xb[i] >> 7) & 0xFFu;
        if (e >= 96u && e <= 142u) ++c;
    }
    atomicAdd(&cnt, c);
    __syncthreads();
    if (threadIdx.x == 0) *flag = (cnt < 2048) ? 1u : 0u;
}

// ---------------------------------------------------------------------------
// Transpose + convert-to-bf16: out[c][r] = bf16(in[r][c]).
// ---------------------------------------------------------------------------
__global__ __launch_bounds__(256)
void transpose_cvt(const void* __restrict__ in, short* __restrict__ out,
                   int R, int C, const unsigned int* __restrict__ flagp)
{
    const bool f32in = (*flagp != 0u);
    __shared__ short tile[64][65];
    const int bx = blockIdx.x * 64;
    const int by = blockIdx.y * 64;
    const int tx = threadIdx.x & 63;
    const int ty = threadIdx.x >> 6;
#pragma unroll
    for (int i = 0; i < 64; i += 4) {
        size_t idx = (size_t)(by + ty + i) * C + bx + tx;
        tile[ty + i][tx] = f32in ? f2bf(((const float*)in)[idx])
                                 : ((const short*)in)[idx];
    }
    __syncthreads();
#pragma unroll
    for (int i = 0; i < 64; i += 4)
        out[(size_t)(bx + ty + i) * R + by + tx] = tile[tx][ty + i];
}

// ---------------------------------------------------------------------------
// GEMM: C = A[M][K] @ B (Bt[N][K] bf16) + bias.  128x128 tile, BK=32.
// Staging via global_load_lds width=16 into UNPADDED stride-32 LDS (m97).
// EPI=1 (QKV): scatter Q,K [BH][T][64], V transposed [BH][64][T].
//   Q outputs are PRE-SCALED by 0.125*log2(e) so attn can use exp2 directly.
// EPI=0 (proj): row-major out, dtype per flag.
// ---------------------------------------------------------------------------
template <int EPI>
__global__ __launch_bounds__(256)
void gemm_kernel(const void* __restrict__ A,
                 const short* __restrict__ Bt,
                 const void* __restrict__ bias,
                 void* __restrict__ O0,
                 short* __restrict__ O1,
                 short* __restrict__ O2,
                 int M, int N, int K,
                 const unsigned int* __restrict__ flagp)
{
    const bool f32io = (*flagp != 0u);
    __shared__ __align__(16) short ldsA[128 * 32];  // [m][k] stride 32, no pad
    __shared__ __align__(16) short ldsB[128 * 32];  // [n][k]

    const int tid = threadIdx.x;
    const int lane = tid & 63;
    const int wv = tid >> 6;
    const int wm = (wv & 1) * 64;
    const int wn = (wv >> 1) * 64;
    const int tile_m = blockIdx.y * 128;
    const int tile_n = blockIdx.x * 128;

    f32x4 acc[4][4];
#pragma unroll
    for (int i = 0; i < 4; ++i)
#pragma unroll
        for (int j = 0; j < 4; ++j) acc[i][j] = (f32x4){0.f, 0.f, 0.f, 0.f};

    const int ar = lane & 15;
    const int aq = (lane >> 4) * 8;
    const int lrow = lane >> 2;          // 0..15
    const int lcol = (lane & 3) << 3;    // 0,8,16,24

    for (int k0 = 0; k0 < K; k0 += 32) {
        if (EPI == 1 && f32io) {
#pragma unroll
            for (int p = 0; p < 2; ++p) {
                int idx = tid + p * 256;
                int row = idx >> 2;
                int col = (idx & 3) << 3;
                const float* Af = (const float*)A;
                const f32x4* fp = (const f32x4*)(Af + (size_t)(tile_m + row) * K + (k0 + col));
                f32x4 u0 = fp[0], u1 = fp[1];
                short8 v;
#pragma unroll
                for (int j = 0; j < 4; ++j) { v[j] = f2bf(u0[j]); v[j + 4] = f2bf(u1[j]); }
                *(short8*)(ldsA + row * 32 + col) = v;
            }
        } else {
            const short* Ag = (const short*)A;
#pragma unroll
            for (int p = 0; p < 2; ++p) {
                int c = wv * 2 + p;
                int row = c * 16 + lrow;
                gload_lds16(Ag + (size_t)(tile_m + row) * K + k0 + lcol, ldsA + c * 512);
            }
        }
#pragma unroll
        for (int p = 0; p < 2; ++p) {
            int c = wv * 2 + p;
            int row = c * 16 + lrow;
            gload_lds16(Bt + (size_t)(tile_n + row) * K + k0 + lcol, ldsB + c * 512);
        }
        __syncthreads();

        short8 af[4], bfr[4];
#pragma unroll
        for (int i = 0; i < 4; ++i)
            af[i] = *(const short8*)(ldsA + (wm + i * 16 + ar) * 32 + aq);
#pragma unroll
        for (int j = 0; j < 4; ++j)
            bfr[j] = *(const short8*)(ldsB + (wn + j * 16 + ar) * 32 + aq);
#pragma unroll
        for (int i = 0; i < 4; ++i)
#pragma unroll
            for (int j = 0; j < 4; ++j)
                acc[i][j] = MFMA16(af[i], bfr[j], acc[i][j]);
        __syncthreads();
    }

    const int colq = lane & 15;
    const int rowq = (lane >> 4) * 4;
#pragma unroll
    for (int j = 0; j < 4; ++j) {
        int gn = tile_n + wn + j * 16 + colq;
        float bv = f32io ? ((const float*)bias)[gn] : bf2f(((const short*)bias)[gn]);
#pragma unroll
        for (int i = 0; i < 4; ++i) {
#pragma unroll
            for (int r = 0; r < 4; ++r) {
                int gm = tile_m + wm + i * 16 + rowq + r;
                float val = acc[i][j][r] + bv;
                if (EPI == 0) {
                    if (f32io) ((float*)O0)[(size_t)gm * N + gn] = val;
                    else       ((short*)O0)[(size_t)gm * N + gn] = f2bf(val);
                } else {
                    int which = gn >> 10;
                    int c = gn & 1023;
                    int h = c >> 6;
                    int d = c & 63;
                    int b = gm >> 11;
                    int t = gm & 2047;
                    size_t bh = (size_t)(b * 16 + h);
                    // Q pre-scaled: scale * log2(e) = 0.125 * 1.44269504...
                    short o = f2bf(which == 0 ? val * 0.18033688011112042f : val);
                    if (which == 0)      ((short*)O0)[(bh * 2048 + t) * 64 + d] = o;
                    else if (which == 1) O1[(bh * 2048 + t) * 64 + d] = o;
                    else                 O2[(bh * 64 + d) * 2048 + t] = o;  // V^T
                }
            }
        }
    }
}

// ---------------------------------------------------------------------------
// Flash attention, causal, fixed-base softmax (exact: |scores| << 88).
// Q,K: [BH][2048][64], Vt: [BH][64][2048] bf16.  Y: [B][T][C] bf16.
//
// R2 restructure (fixing R1's imbalance while keeping its L2 win):
//  - PARITY-SPLIT PAIR JOBS: block = 2 waves, both working pair (g, 127-g)
//    sequentially; wave p handles k-tiles kt ≡ p (mod 2).  Every wave costs
//    33±1 iterations -> UNIFORM grid-wide (R1's tail was avg/max = 52%).
//    8192 waves = 8 waves/SIMD (VGPR must stay <=64 — check VGPR_Count).
//    Partial O / row-sums combined per pass via LDS (+1 barrier per pass).
//  - XCD-AWARE swizzle kept: each XCD owns 8 bh values -> K/V L2-resident
//    (R1 measured: FETCH 650MB -> 24.6MB).
//  - Q pre-scaled by 0.125*log2(e) in GEMM epilogue: exp2f(s) directly,
//    8 fewer v_mul per iteration.
//
// SOFTWARE PIPELINE per iteration unchanged: V(kt) loads; QK on prefetched
// K; issue K(kt+2) loads; exp/mask/P-store (hides V+K latency); P LDS
// round-trip; PV.  P stride 36 shorts -> conflict-free ds_write.
// ---------------------------------------------------------------------------
__global__ __launch_bounds__(128)
void attn_kernel(const short* __restrict__ Q,
                 const short* __restrict__ Kp_,
                 const short* __restrict__ Vt,
                 short* __restrict__ Y)
{
    __shared__ __align__(16) short pbuf[2][16 * 36];  // per-wave P [16 q][32 k]
    __shared__ __align__(16) float cbuf[16][68];      // combine: O partials
    __shared__ float lbuf[16];                        // combine: row-sum partials

    const int tid = threadIdx.x;
    const int lane = tid & 63;
    const int wv = tid >> 6;                  // 0..1 = k-tile parity
    const int m16 = lane & 15;
    const int quad = lane >> 4;

    // XCD-aware decode: 4096 blocks; xcd = fid&7 (HW round-robin),
    // 8 bh per XCD, 64 consecutive blocks (pairs) per bh.
    const int fid = blockIdx.x;
    const int xcd = fid & 7;
    const int slot = fid >> 3;                // 0..511
    const int bh = (xcd << 3) | (slot >> 6);  // 0..63
    const int g = slot & 63;                  // pair id 0..63

    const int b = bh >> 4, h = bh & 15;

    const short* Qp = Q   + (size_t)bh * 2048 * 64;
    const short* Kp = Kp_ + (size_t)bh * 2048 * 64;
    const short* Vp = Vt  + (size_t)bh * 64 * 2048;
    short* pw = pbuf[wv];

#pragma unroll
    for (int pass = 0; pass < 2; ++pass) {
        const int t16 = pass ? (127 - g) : g;     // 16-row tile index
        const int qtile = t16 * 16;

        short8 aq0 = *(const short8*)(Qp + (size_t)(qtile + m16) * 64 + quad * 8);
        short8 aq1 = *(const short8*)(Qp + (size_t)(qtile + m16) * 64 + 32 + quad * 8);

        f32x4 o[4];
#pragma unroll
        for (int dt = 0; dt < 4; ++dt) o[dt] = (f32x4){0.f, 0.f, 0.f, 0.f};
        float lrow[4] = {0.f, 0.f, 0.f, 0.f};

        const int nkt = (t16 >> 1) + 1;           // 32-key tiles

        // prefetch K(wv): this wave's first tile (kb<=32 always in-bounds)
        short8 bk0, bk1, bk2, bk3;
        {
            const short* K0 = Kp + (size_t)(wv * 32 + m16) * 64 + quad * 8;
            bk0 = *(const short8*)(K0);
            bk1 = *(const short8*)(K0 + 32);
            bk2 = *(const short8*)(K0 + 16 * 64);
            bk3 = *(const short8*)(K0 + 16 * 64 + 32);
        }

        for (int kt = wv; kt < nkt; kt += 2) {
            const int kb = kt << 5;
            // V(kt) loads first — independent, latency hidden under QK+exp
            const short* V0 = Vp + (size_t)m16 * 2048 + kb + quad * 8;
            short8 bv0 = *(const short8*)(V0);
            short8 bv1 = *(const short8*)(V0 + (size_t)16 * 2048);
            short8 bv2 = *(const short8*)(V0 + (size_t)32 * 2048);
            short8 bv3 = *(const short8*)(V0 + (size_t)48 * 2048);

            // QK on prefetched K
            f32x4 s0 = (f32x4){0.f, 0.f, 0.f, 0.f};
            f32x4 s1 = (f32x4){0.f, 0.f, 0.f, 0.f};
            s0 = MFMA16(aq0, bk0, s0);
            s0 = MFMA16(aq1, bk1, s0);
            s1 = MFMA16(aq0, bk2, s1);
            s1 = MFMA16(aq1, bk3, s1);

            // prefetch K(kt+2) (clamped; latency hidden under exp section)
            {
                const int kbn = (kt + 2 < nkt) ? (kb + 64) : kb;
                const short* Kn = Kp + (size_t)(kbn + m16) * 64 + quad * 8;
                bk0 = *(const short8*)(Kn);
                bk1 = *(const short8*)(Kn + 32);
                bk2 = *(const short8*)(Kn + 16 * 64);
                bk3 = *(const short8*)(Kn + 16 * 64 + 32);
            }

            // exp + mask + P store (fixed-base softmax; Q pre-scaled)
#pragma unroll
            for (int c = 0; c < 2; ++c) {
                const f32x4 sv = c ? s1 : s0;
                const int key = kb + c * 16 + m16;
                const bool needmask = (kb + c * 16 + 15 > qtile);
#pragma unroll
                for (int r = 0; r < 4; ++r) {
                    float p = exp2f(sv[r]);
                    if (needmask && key > qtile + quad * 4 + r) p = 0.f;
                    lrow[r] += p;
                    pw[(quad * 4 + r) * 36 + c * 16 + m16] = f2bf(p);
                }
            }

            // P (C-layout) -> A-operand via per-wave LDS round-trip
            asm volatile("" ::: "memory");
            short8 ap = *(const short8*)(pw + m16 * 36 + quad * 8);
            asm volatile("" ::: "memory");

            // PV — V already arrived (issued at top of iteration)
            o[0] = MFMA16(ap, bv0, o[0]);
            o[1] = MFMA16(ap, bv1, o[1]);
            o[2] = MFMA16(ap, bv2, o[2]);
            o[3] = MFMA16(ap, bv3, o[3]);
        }

        // wave-internal row-sum reduce over the 16 m16 lanes
        float rsum[4];
#pragma unroll
        for (int r = 0; r < 4; ++r) {
            float sm = lrow[r];
#pragma unroll
            for (int off = 1; off < 16; off <<= 1)
                sm += __shfl_xor(sm, off);
            rsum[r] = sm;
        }

        // cross-wave combine: wv1 -> LDS, wv0 adds + writes output
        if (wv == 1) {
#pragma unroll
            for (int dt = 0; dt < 4; ++dt)
#pragma unroll
                for (int r = 0; r < 4; ++r)
                    cbuf[quad * 4 + r][dt * 16 + m16] = o[dt][r];
            if (m16 == 0) {
#pragma unroll
                for (int r = 0; r < 4; ++r) lbuf[quad * 4 + r] = rsum[r];
            }
        }
        __syncthreads();
        if (wv == 0) {
            float linv[4];
#pragma unroll
            for (int r = 0; r < 4; ++r)
                linv[r] = 1.0f / (rsum[r] + lbuf[quad * 4 + r]);
#pragma unroll
            for (int dt = 0; dt < 4; ++dt) {
#pragma unroll
                for (int r = 0; r < 4; ++r) {
                    int row = qtile + quad * 4 + r;
                    int col = h * 64 + dt * 16 + m16;
                    float val = o[dt][r] + cbuf[quad * 4 + r][dt * 16 + m16];
                    Y[((size_t)(b * 2048 + row)) * 1024 + col] = f2bf(val * linv[r]);
                }
            }
        }
        __syncthreads();  // cbuf/lbuf reused next pass
    }
}

// ---------------------------------------------------------------------------
extern "C" void kernel_launch(void* const* d_in, const int* in_sizes, int n_in,
                              void* d_out, int out_size, void* d_ws, size_t ws_size,
                              hipStream_t stream)
{
    const void* x      = d_in[0];
    const void* w_attn = d_in[1];
    const void* b_attn = d_in[2];
    const void* w_proj = d_in[3];
    const void* b_proj = d_in[4];

    char* ws = (char*)d_ws;
    unsigned int* flag = (unsigned int*)(ws + 0);
    short* Wta = (short*)(ws + 256);
    short* Wtp = (short*)(ws + 6291712);
    short* Qb  = (short*)(ws + 8388864);
    short* Kb  = (short*)(ws + 25166080);
    short* Vtb = (short*)(ws + 41943296);
    short* Yb  = (short*)(ws + 58720512);

    sniff_kernel<<<1, 256, 0, stream>>>((const unsigned int*)x, flag);
    transpose_cvt<<<dim3(48, 16), 256, 0, stream>>>(w_attn, Wta, 1024, 3072, flag);
    transpose_cvt<<<dim3(16, 16), 256, 0, stream>>>(w_proj, Wtp, 1024, 1024, flag);
    gemm_kernel<1><<<dim3(24, 64), 256, 0, stream>>>(x, Wta, b_attn, Qb, Kb, Vtb,
                                                     8192, 3072, 1024, flag);
    attn_kernel<<<dim3(4096), 128, 0, stream>>>(Qb, Kb, Vtb, Yb);
    gemm_kernel<0><<<dim3(8, 64), 256, 0, stream>>>(Yb, Wtp, b_proj, d_out, nullptr, nullptr,
                                                    8192, 1024, 1024, flag);
}

// Round 3
// 344.047 us; speedup vs baseline: 1.5538x; 1.4774x over previous
//
#include <hip/hip_runtime.h>
#include <hip/hip_bf16.h>
#include <math.h>

// B=4, T=2048, C=1024, H=16, Dh=64.

typedef __attribute__((ext_vector_type(8))) short short8;   // 8 bf16 (4 VGPRs)
typedef __attribute__((ext_vector_type(4))) float f32x4;

__device__ __forceinline__ short f2bf(float f) {
    __hip_bfloat16 h = __float2bfloat16(f);
    return *reinterpret_cast<short*>(&h);
}
__device__ __forceinline__ float bf2f(short s) {
    __hip_bfloat16 h = *reinterpret_cast<__hip_bfloat16*>(&s);
    return __bfloat162float(h);
}

#define MFMA16(a, b, c) __builtin_amdgcn_mfma_f32_16x16x32_bf16((a), (b), (c), 0, 0, 0)

// async 16B global->LDS (lds dest: wave-uniform base + lane*16)
__device__ __forceinline__ void gload_lds16(const short* g, short* l) {
    __builtin_amdgcn_global_load_lds(
        (const __attribute__((address_space(1))) void*)g,
        (__attribute__((address_space(3))) void*)l, 16, 0, 0);
}

// ---------------------------------------------------------------------------
// Dtype sniff: fp32 inputs (flag=1) vs bf16 (flag=0).
// ---------------------------------------------------------------------------
__global__ void sniff_kernel(const unsigned int* __restrict__ xb,
                             unsigned int* __restrict__ flag)
{
    __shared__ int cnt;
    if (threadIdx.x == 0) cnt = 0;
    __syncthreads();
    int c = 0;
    for (int i = threadIdx.x; i < 4096; i += 256) {
        unsigned e = (xb[i] >> 7) & 0xFFu;
        if (e >= 96u && e <= 142u) ++c;
    }
    atomicAdd(&cnt, c);
    __syncthreads();
    if (threadIdx.x == 0) *flag = (cnt < 2048) ? 1u : 0u;
}

// ---------------------------------------------------------------------------
// Transpose + convert-to-bf16: out[c][r] = bf16(in[r][c]).
// ---------------------------------------------------------------------------
__global__ __launch_bounds__(256)
void transpose_cvt(const void* __restrict__ in, short* __restrict__ out,
                   int R, int C, const unsigned int* __restrict__ flagp)
{
    const bool f32in = (*flagp != 0u);
    __shared__ short tile[64][65];
    const int bx = blockIdx.x * 64;
    const int by = blockIdx.y * 64;
    const int tx = threadIdx.x & 63;
    const int ty = threadIdx.x >> 6;
#pragma unroll
    for (int i = 0; i < 64; i += 4) {
        size_t idx = (size_t)(by + ty + i) * C + bx + tx;
        tile[ty + i][tx] = f32in ? f2bf(((const float*)in)[idx])
                                 : ((const short*)in)[idx];
    }
    __syncthreads();
#pragma unroll
    for (int i = 0; i < 64; i += 4)
        out[(size_t)(bx + ty + i) * R + by + tx] = tile[tx][ty + i];
}

// ---------------------------------------------------------------------------
// GEMM: C = A[M][K] @ B (Bt[N][K] bf16) + bias.  128x128 tile, BK=32.
// Staging via global_load_lds width=16 into UNPADDED stride-32 LDS (m97).
// EPI=1 (QKV): scatter Q,K [BH][T][64], V transposed [BH][64][T].
//   Q outputs are PRE-SCALED by 0.125*log2(e) so attn can use exp2 directly.
// EPI=0 (proj): row-major out, dtype per flag.
// ---------------------------------------------------------------------------
template <int EPI>
__global__ __launch_bounds__(256)
void gemm_kernel(const void* __restrict__ A,
                 const short* __restrict__ Bt,
                 const void* __restrict__ bias,
                 void* __restrict__ O0,
                 short* __restrict__ O1,
                 short* __restrict__ O2,
                 int M, int N, int K,
                 const unsigned int* __restrict__ flagp)
{
    const bool f32io = (*flagp != 0u);
    __shared__ __align__(16) short ldsA[128 * 32];  // [m][k] stride 32, no pad
    __shared__ __align__(16) short ldsB[128 * 32];  // [n][k]

    const int tid = threadIdx.x;
    const int lane = tid & 63;
    const int wv = tid >> 6;
    const int wm = (wv & 1) * 64;
    const int wn = (wv >> 1) * 64;
    const int tile_m = blockIdx.y * 128;
    const int tile_n = blockIdx.x * 128;

    f32x4 acc[4][4];
#pragma unroll
    for (int i = 0; i < 4; ++i)
#pragma unroll
        for (int j = 0; j < 4; ++j) acc[i][j] = (f32x4){0.f, 0.f, 0.f, 0.f};

    const int ar = lane & 15;
    const int aq = (lane >> 4) * 8;
    const int lrow = lane >> 2;          // 0..15
    const int lcol = (lane & 3) << 3;    // 0,8,16,24

    for (int k0 = 0; k0 < K; k0 += 32) {
        if (EPI == 1 && f32io) {
#pragma unroll
            for (int p = 0; p < 2; ++p) {
                int idx = tid + p * 256;
                int row = idx >> 2;
                int col = (idx & 3) << 3;
                const float* Af = (const float*)A;
                const f32x4* fp = (const f32x4*)(Af + (size_t)(tile_m + row) * K + (k0 + col));
                f32x4 u0 = fp[0], u1 = fp[1];
                short8 v;
#pragma unroll
                for (int j = 0; j < 4; ++j) { v[j] = f2bf(u0[j]); v[j + 4] = f2bf(u1[j]); }
                *(short8*)(ldsA + row * 32 + col) = v;
            }
        } else {
            const short* Ag = (const short*)A;
#pragma unroll
            for (int p = 0; p < 2; ++p) {
                int c = wv * 2 + p;
                int row = c * 16 + lrow;
                gload_lds16(Ag + (size_t)(tile_m + row) * K + k0 + lcol, ldsA + c * 512);
            }
        }
#pragma unroll
        for (int p = 0; p < 2; ++p) {
            int c = wv * 2 + p;
            int row = c * 16 + lrow;
            gload_lds16(Bt + (size_t)(tile_n + row) * K + k0 + lcol, ldsB + c * 512);
        }
        __syncthreads();

        short8 af[4], bfr[4];
#pragma unroll
        for (int i = 0; i < 4; ++i)
            af[i] = *(const short8*)(ldsA + (wm + i * 16 + ar) * 32 + aq);
#pragma unroll
        for (int j = 0; j < 4; ++j)
            bfr[j] = *(const short8*)(ldsB + (wn + j * 16 + ar) * 32 + aq);
#pragma unroll
        for (int i = 0; i < 4; ++i)
#pragma unroll
            for (int j = 0; j < 4; ++j)
                acc[i][j] = MFMA16(af[i], bfr[j], acc[i][j]);
        __syncthreads();
    }

    const int colq = lane & 15;
    const int rowq = (lane >> 4) * 4;
#pragma unroll
    for (int j = 0; j < 4; ++j) {
        int gn = tile_n + wn + j * 16 + colq;
        float bv = f32io ? ((const float*)bias)[gn] : bf2f(((const short*)bias)[gn]);
#pragma unroll
        for (int i = 0; i < 4; ++i) {
#pragma unroll
            for (int r = 0; r < 4; ++r) {
                int gm = tile_m + wm + i * 16 + rowq + r;
                float val = acc[i][j][r] + bv;
                if (EPI == 0) {
                    if (f32io) ((float*)O0)[(size_t)gm * N + gn] = val;
                    else       ((short*)O0)[(size_t)gm * N + gn] = f2bf(val);
                } else {
                    int which = gn >> 10;
                    int c = gn & 1023;
                    int h = c >> 6;
                    int d = c & 63;
                    int b = gm >> 11;
                    int t = gm & 2047;
                    size_t bh = (size_t)(b * 16 + h);
                    // Q pre-scaled: scale * log2(e) = 0.125 * 1.44269504...
                    short o = f2bf(which == 0 ? val * 0.18033688011112042f : val);
                    if (which == 0)      ((short*)O0)[(bh * 2048 + t) * 64 + d] = o;
                    else if (which == 1) O1[(bh * 2048 + t) * 64 + d] = o;
                    else                 O2[(bh * 64 + d) * 2048 + t] = o;  // V^T
                }
            }
        }
    }
}

// ---------------------------------------------------------------------------
// Flash attention, causal, fixed-base softmax (exact: |scores| << 88).
// Q,K: [BH][2048][64], Vt: [BH][64][2048] bf16.  Y: [B][T][C] bf16.
//
// R3 restructure (LDS-staged K/V — kills both suspects from R0-R2):
//  - Block = 4 waves, 64 Q-rows (16/wave).  K/V tile (64 keys x 64d + V^T
//    64d x 64 keys = 16KB) staged ONCE per block via global_load_lds ->
//    L2-side traffic /4 (2.1GB -> ~540MB) AND staging has no dest VGPRs,
//    so the compiler cannot sink the prefetch (R0-R2's suspected fiction).
//  - XOR-SWIZZLED tiles (G4/rule 21): row-major [64][128B] read by 16-lane
//    column slices is a 16-way bank conflict.  DMA dest stays linear; the
//    per-lane GLOBAL source address is pre-swizzled; reads apply the same
//    XOR ->  <=2 lanes/bank (free).  sw = ((lane&7)^((lane>>3)&7))*8 shorts.
//  - Jobs: block = tile pair (t, 31-t) -> 33 uniform 64-key steps.
//    1024 blocks, XCD-chunked (8 bh/XCD -> K/V L2-resident).
//  - Safe 2-barrier single-buffer structure: stage; __syncthreads (drains
//    vmcnt); compute from LDS; __syncthreads.  Overlap across the 4
//    resident blocks/CU, not within a block (no raw-barrier race risk).
//  - launch_bounds(256,4): VGPR <=128 so 4 blocks/CU stay resident.
// ---------------------------------------------------------------------------
__global__ __launch_bounds__(256, 4)
void attn_kernel(const short* __restrict__ Q,
                 const short* __restrict__ Kp_,
                 const short* __restrict__ Vt,
                 short* __restrict__ Y)
{
    __shared__ __align__(16) short ldsK[64 * 64];     // [key][d], swizzled
    __shared__ __align__(16) short ldsV[64 * 64];     // [d][key], swizzled
    __shared__ __align__(16) short pbuf[4][16 * 72];  // per-wave P [16 q][64 k]

    const int tid = threadIdx.x;
    const int lane = tid & 63;
    const int wv = tid >> 6;                  // 0..3
    const int m16 = lane & 15;
    const int quad = lane >> 4;

    // XCD-aware decode: 1024 blocks; xcd = fid&7; 8 bh per XCD;
    // 16 consecutive blocks (tile pairs) per bh.
    const int fid = blockIdx.x;
    const int xcd = fid & 7;
    const int slot = fid >> 3;                // 0..127
    const int bh = (xcd << 3) | (slot >> 4);  // 0..63
    const int g = slot & 15;                  // pair id 0..15

    const int b = bh >> 4, h = bh & 15;

    const short* Qp = Q   + (size_t)bh * 2048 * 64;
    const short* Kp = Kp_ + (size_t)bh * 2048 * 64;
    const short* Vp = Vt  + (size_t)bh * 64 * 2048;
    short* pw = pbuf[wv];

    // per-lane staging constants: 8 rows/wave-call, slot = lane&7 (16B units)
    const int srow = lane >> 3;                           // 0..7 within call
    const int sw = (((lane & 7) ^ (srow & 7)) << 3);      // swizzled col, shorts
    const int swr = ((m16 & 7) << 3);                     // read-side XOR, shorts

#pragma unroll
    for (int pass = 0; pass < 2; ++pass) {
        const int t = pass ? (31 - g) : g;        // 64-row tile index 0..31
        const int qbase = t * 64 + wv * 16;       // this wave's 16 q-rows

        short8 aq0 = *(const short8*)(Qp + (size_t)(qbase + m16) * 64 + quad * 8);
        short8 aq1 = *(const short8*)(Qp + (size_t)(qbase + m16) * 64 + 32 + quad * 8);

        f32x4 o[4];
#pragma unroll
        for (int dt = 0; dt < 4; ++dt) o[dt] = (f32x4){0.f, 0.f, 0.f, 0.f};
        float lrow[4] = {0.f, 0.f, 0.f, 0.f};

        for (int kt = 0; kt <= t; ++kt) {
            const int kb = kt << 6;

            // ---- stage K [64 key][64 d] and V^T [64 d][64 key] tiles ----
            // wave wv covers rows (wv*2+p)*8 + srow; dest linear, source
            // pre-swizzled so that LDS[row][col ^ ((row&7)<<3)] = data.
#pragma unroll
            for (int p = 0; p < 2; ++p) {
                const int c8 = wv * 2 + p;
                const int row = c8 * 8 + srow;
                gload_lds16(Kp + (size_t)(kb + row) * 64 + sw, ldsK + c8 * 512);
                gload_lds16(Vp + (size_t)row * 2048 + kb + sw, ldsV + c8 * 512);
            }
            __syncthreads();   // drains vmcnt(0): tiles complete

            // ---- QK^T: 4 key-blocks x 2 k-chunks ----
            f32x4 s[4];
#pragma unroll
            for (int c = 0; c < 4; ++c) {
                const short* kr = ldsK + (c * 16 + m16) * 64;
                short8 kf0 = *(const short8*)(kr + ((quad * 8) ^ swr));
                short8 kf1 = *(const short8*)(kr + ((quad * 8 + 32) ^ swr));
                f32x4 z = (f32x4){0.f, 0.f, 0.f, 0.f};
                z = MFMA16(aq0, kf0, z);
                z = MFMA16(aq1, kf1, z);
                s[c] = z;
            }

            // ---- exp + causal mask + P store (fixed-base; Q pre-scaled) ----
#pragma unroll
            for (int c = 0; c < 4; ++c) {
                const int key = kb + c * 16 + m16;
                const bool needmask = (kb + c * 16 + 15 > qbase);
#pragma unroll
                for (int r = 0; r < 4; ++r) {
                    float p = exp2f(s[c][r]);
                    if (needmask && key > qbase + quad * 4 + r) p = 0.f;
                    lrow[r] += p;
                    pw[(quad * 4 + r) * 72 + c * 16 + m16] = f2bf(p);
                }
            }

            // P (C-layout) -> A-operand via per-wave LDS round-trip
            asm volatile("" ::: "memory");
            short8 ap0 = *(const short8*)(pw + m16 * 72 + quad * 8);
            short8 ap1 = *(const short8*)(pw + m16 * 72 + quad * 8 + 32);
            asm volatile("" ::: "memory");

            // ---- PV: 4 d-blocks x 2 k-chunks ----
#pragma unroll
            for (int dt = 0; dt < 4; ++dt) {
                const short* vr = ldsV + (dt * 16 + m16) * 64;
                short8 vf0 = *(const short8*)(vr + ((quad * 8) ^ swr));
                short8 vf1 = *(const short8*)(vr + ((quad * 8 + 32) ^ swr));
                o[dt] = MFMA16(ap0, vf0, o[dt]);
                o[dt] = MFMA16(ap1, vf1, o[dt]);
            }
            __syncthreads();   // all reads done before next stage overwrites
        }

        // row-sum reduce over the 16 key-lanes (xor within m16 group)
        float linv[4];
#pragma unroll
        for (int r = 0; r < 4; ++r) {
            float sm = lrow[r];
#pragma unroll
            for (int off = 1; off < 16; off <<= 1)
                sm += __shfl_xor(sm, off);
            linv[r] = 1.0f / sm;
        }
#pragma unroll
        for (int dt = 0; dt < 4; ++dt) {
#pragma unroll
            for (int r = 0; r < 4; ++r) {
                int row = qbase + quad * 4 + r;
                int col = h * 64 + dt * 16 + m16;
                Y[((size_t)(b * 2048 + row)) * 1024 + col] = f2bf(o[dt][r] * linv[r]);
            }
        }
        // no barrier needed here: pass-1 staging is guarded by the loop's
        // trailing __syncthreads (LDS reads all completed before it).
    }
}

// ---------------------------------------------------------------------------
extern "C" void kernel_launch(void* const* d_in, const int* in_sizes, int n_in,
                              void* d_out, int out_size, void* d_ws, size_t ws_size,
                              hipStream_t stream)
{
    const void* x      = d_in[0];
    const void* w_attn = d_in[1];
    const void* b_attn = d_in[2];
    const void* w_proj = d_in[3];
    const void* b_proj = d_in[4];

    char* ws = (char*)d_ws;
    unsigned int* flag = (unsigned int*)(ws + 0);
    short* Wta = (short*)(ws + 256);
    short* Wtp = (short*)(ws + 6291712);
    short* Qb  = (short*)(ws + 8388864);
    short* Kb  = (short*)(ws + 25166080);
    short* Vtb = (short*)(ws + 41943296);
    short* Yb  = (short*)(ws + 58720512);

    sniff_kernel<<<1, 256, 0, stream>>>((const unsigned int*)x, flag);
    transpose_cvt<<<dim3(48, 16), 256, 0, stream>>>(w_attn, Wta, 1024, 3072, flag);
    transpose_cvt<<<dim3(16, 16), 256, 0, stream>>>(w_proj, Wtp, 1024, 1024, flag);
    gemm_kernel<1><<<dim3(24, 64), 256, 0, stream>>>(x, Wta, b_attn, Qb, Kb, Vtb,
                                                     8192, 3072, 1024, flag);
    attn_kernel<<<dim3(1024), 256, 0, stream>>>(Qb, Kb, Vtb, Yb);
    gemm_kernel<0><<<dim3(8, 64), 256, 0, stream>>>(Yb, Wtp, b_proj, d_out, nullptr, nullptr,
                                                    8192, 1024, 1024, flag);
}

// Round 4
// 324.777 us; speedup vs baseline: 1.6460x; 1.0593x over previous
//
#include <hip/hip_runtime.h>
#include <hip/hip_bf16.h>
#include <math.h>

// B=4, T=2048, C=1024, H=16, Dh=64.

typedef __attribute__((ext_vector_type(8))) short short8;   // 8 bf16 (4 VGPRs)
typedef __attribute__((ext_vector_type(4))) float f32x4;

__device__ __forceinline__ short f2bf(float f) {
    __hip_bfloat16 h = __float2bfloat16(f);
    return *reinterpret_cast<short*>(&h);
}
__device__ __forceinline__ float bf2f(short s) {
    __hip_bfloat16 h = *reinterpret_cast<__hip_bfloat16*>(&s);
    return __bfloat162float(h);
}

#define MFMA16(a, b, c) __builtin_amdgcn_mfma_f32_16x16x32_bf16((a), (b), (c), 0, 0, 0)

// async 16B global->LDS (lds dest: wave-uniform base + lane*16)
__device__ __forceinline__ void gload_lds16(const short* g, short* l) {
    __builtin_amdgcn_global_load_lds(
        (const __attribute__((address_space(1))) void*)g,
        (__attribute__((address_space(3))) void*)l, 16, 0, 0);
}

// ---------------------------------------------------------------------------
// Dtype sniff: fp32 inputs (flag=1) vs bf16 (flag=0).
// ---------------------------------------------------------------------------
__global__ void sniff_kernel(const unsigned int* __restrict__ xb,
                             unsigned int* __restrict__ flag)
{
    __shared__ int cnt;
    if (threadIdx.x == 0) cnt = 0;
    __syncthreads();
    int c = 0;
    for (int i = threadIdx.x; i < 4096; i += 256) {
        unsigned e = (xb[i] >> 7) & 0xFFu;
        if (e >= 96u && e <= 142u) ++c;
    }
    atomicAdd(&cnt, c);
    __syncthreads();
    if (threadIdx.x == 0) *flag = (cnt < 2048) ? 1u : 0u;
}

// ---------------------------------------------------------------------------
// R4: x -> bf16 (or straight copy if already bf16).  8192x1024 elems,
// 8 per thread, 4096 blocks.  ~48MB traffic ≈ 8 µs at HBM rate.
// Removes the fp32 VGPR-round-trip staging from the QKV GEMM's K-loop so
// the GEMM runs the verified m97 pure-global_load_lds path.
// ---------------------------------------------------------------------------
__global__ __launch_bounds__(256)
void cvt_x(const void* __restrict__ in, short* __restrict__ out,
           const unsigned int* __restrict__ flagp)
{
    const bool f32in = (*flagp != 0u);
    const size_t i = ((size_t)blockIdx.x * 256 + threadIdx.x) * 8;
    if (f32in) {
        const float* f = (const float*)in + i;
        f32x4 u0 = *(const f32x4*)f;
        f32x4 u1 = *(const f32x4*)(f + 4);
        short8 v;
#pragma unroll
        for (int j = 0; j < 4; ++j) { v[j] = f2bf(u0[j]); v[j + 4] = f2bf(u1[j]); }
        *(short8*)(out + i) = v;
    } else {
        *(short8*)(out + i) = *(const short8*)((const short*)in + i);
    }
}

// ---------------------------------------------------------------------------
// Transpose + convert-to-bf16: out[c][r] = bf16(in[r][c]).
// ---------------------------------------------------------------------------
__global__ __launch_bounds__(256)
void transpose_cvt(const void* __restrict__ in, short* __restrict__ out,
                   int R, int C, const unsigned int* __restrict__ flagp)
{
    const bool f32in = (*flagp != 0u);
    __shared__ short tile[64][65];
    const int bx = blockIdx.x * 64;
    const int by = blockIdx.y * 64;
    const int tx = threadIdx.x & 63;
    const int ty = threadIdx.x >> 6;
#pragma unroll
    for (int i = 0; i < 64; i += 4) {
        size_t idx = (size_t)(by + ty + i) * C + bx + tx;
        tile[ty + i][tx] = f32in ? f2bf(((const float*)in)[idx])
                                 : ((const short*)in)[idx];
    }
    __syncthreads();
#pragma unroll
    for (int i = 0; i < 64; i += 4)
        out[(size_t)(bx + ty + i) * R + by + tx] = tile[tx][ty + i];
}

// ---------------------------------------------------------------------------
// GEMM: C = A[M][K] (bf16) @ B (Bt[N][K] bf16) + bias.  128x128 tile, BK=32.
// Pure m97 structure: BOTH operands staged via global_load_lds width=16
// into UNPADDED stride-32 LDS (no VALU in staging path, not sinkable).
// EPI=1 (QKV): scatter Q,K [BH][T][64], V transposed [BH][64][T].
//   Q outputs are PRE-SCALED by 0.125*log2(e) so attn can use exp2 directly.
// EPI=0 (proj): row-major out, dtype per flag.
// ---------------------------------------------------------------------------
template <int EPI>
__global__ __launch_bounds__(256)
void gemm_kernel(const short* __restrict__ A,
                 const short* __restrict__ Bt,
                 const void* __restrict__ bias,
                 void* __restrict__ O0,
                 short* __restrict__ O1,
                 short* __restrict__ O2,
                 int M, int N, int K,
                 const unsigned int* __restrict__ flagp)
{
    const bool f32io = (*flagp != 0u);
    __shared__ __align__(16) short ldsA[128 * 32];  // [m][k] stride 32, no pad
    __shared__ __align__(16) short ldsB[128 * 32];  // [n][k]

    const int tid = threadIdx.x;
    const int lane = tid & 63;
    const int wv = tid >> 6;
    const int wm = (wv & 1) * 64;
    const int wn = (wv >> 1) * 64;
    const int tile_m = blockIdx.y * 128;
    const int tile_n = blockIdx.x * 128;

    f32x4 acc[4][4];
#pragma unroll
    for (int i = 0; i < 4; ++i)
#pragma unroll
        for (int j = 0; j < 4; ++j) acc[i][j] = (f32x4){0.f, 0.f, 0.f, 0.f};

    const int ar = lane & 15;
    const int aq = (lane >> 4) * 8;
    const int lrow = lane >> 2;          // 0..15
    const int lcol = (lane & 3) << 3;    // 0,8,16,24

    for (int k0 = 0; k0 < K; k0 += 32) {
#pragma unroll
        for (int p = 0; p < 2; ++p) {
            int c = wv * 2 + p;
            int row = c * 16 + lrow;
            gload_lds16(A + (size_t)(tile_m + row) * K + k0 + lcol, ldsA + c * 512);
            gload_lds16(Bt + (size_t)(tile_n + row) * K + k0 + lcol, ldsB + c * 512);
        }
        __syncthreads();

        short8 af[4], bfr[4];
#pragma unroll
        for (int i = 0; i < 4; ++i)
            af[i] = *(const short8*)(ldsA + (wm + i * 16 + ar) * 32 + aq);
#pragma unroll
        for (int j = 0; j < 4; ++j)
            bfr[j] = *(const short8*)(ldsB + (wn + j * 16 + ar) * 32 + aq);
#pragma unroll
        for (int i = 0; i < 4; ++i)
#pragma unroll
            for (int j = 0; j < 4; ++j)
                acc[i][j] = MFMA16(af[i], bfr[j], acc[i][j]);
        __syncthreads();
    }

    const int colq = lane & 15;
    const int rowq = (lane >> 4) * 4;
#pragma unroll
    for (int j = 0; j < 4; ++j) {
        int gn = tile_n + wn + j * 16 + colq;
        float bv = f32io ? ((const float*)bias)[gn] : bf2f(((const short*)bias)[gn]);
#pragma unroll
        for (int i = 0; i < 4; ++i) {
#pragma unroll
            for (int r = 0; r < 4; ++r) {
                int gm = tile_m + wm + i * 16 + rowq + r;
                float val = acc[i][j][r] + bv;
                if (EPI == 0) {
                    if (f32io) ((float*)O0)[(size_t)gm * N + gn] = val;
                    else       ((short*)O0)[(size_t)gm * N + gn] = f2bf(val);
                } else {
                    int which = gn >> 10;
                    int c = gn & 1023;
                    int h = c >> 6;
                    int d = c & 63;
                    int b = gm >> 11;
                    int t = gm & 2047;
                    size_t bh = (size_t)(b * 16 + h);
                    // Q pre-scaled: scale * log2(e) = 0.125 * 1.44269504...
                    short o = f2bf(which == 0 ? val * 0.18033688011112042f : val);
                    if (which == 0)      ((short*)O0)[(bh * 2048 + t) * 64 + d] = o;
                    else if (which == 1) O1[(bh * 2048 + t) * 64 + d] = o;
                    else                 O2[(bh * 64 + d) * 2048 + t] = o;  // V^T
                }
            }
        }
    }
}

// ---------------------------------------------------------------------------
// Flash attention, causal, fixed-base softmax (exact: |scores| << 88).
// Q,K: [BH][2048][64], Vt: [BH][64][2048] bf16.  Y: [B][T][C] bf16.
//
// R3 structure (verified: attn dropped out of top-5, <143 µs):
//  - Block = 4 waves, 64 Q-rows.  K/V tile staged once per block via
//    global_load_lds (no dest VGPRs -> not sinkable; traffic /4).
//  - XOR-swizzled tiles (G4/rule 21): linear DMA dest, pre-swizzled global
//    source, same XOR on reads -> conflict-free column-slice ds_read_b128.
//  - Block = tile pair (t, 31-t) -> 33 uniform 64-key steps; 1024 blocks,
//    XCD-chunked (8 bh/XCD -> K/V L2-resident).
//  - Safe 2-barrier single-buffer; overlap across 4 resident blocks/CU.
// ---------------------------------------------------------------------------
__global__ __launch_bounds__(256, 4)
void attn_kernel(const short* __restrict__ Q,
                 const short* __restrict__ Kp_,
                 const short* __restrict__ Vt,
                 short* __restrict__ Y)
{
    __shared__ __align__(16) short ldsK[64 * 64];     // [key][d], swizzled
    __shared__ __align__(16) short ldsV[64 * 64];     // [d][key], swizzled
    __shared__ __align__(16) short pbuf[4][16 * 72];  // per-wave P [16 q][64 k]

    const int tid = threadIdx.x;
    const int lane = tid & 63;
    const int wv = tid >> 6;                  // 0..3
    const int m16 = lane & 15;
    const int quad = lane >> 4;

    // XCD-aware decode: 1024 blocks; xcd = fid&7; 8 bh per XCD;
    // 16 consecutive blocks (tile pairs) per bh.
    const int fid = blockIdx.x;
    const int xcd = fid & 7;
    const int slot = fid >> 3;                // 0..127
    const int bh = (xcd << 3) | (slot >> 4);  // 0..63
    const int g = slot & 15;                  // pair id 0..15

    const int b = bh >> 4, h = bh & 15;

    const short* Qp = Q   + (size_t)bh * 2048 * 64;
    const short* Kp = Kp_ + (size_t)bh * 2048 * 64;
    const short* Vp = Vt  + (size_t)bh * 64 * 2048;
    short* pw = pbuf[wv];

    // per-lane staging constants: 8 rows/wave-call, slot = lane&7 (16B units)
    const int srow = lane >> 3;                           // 0..7 within call
    const int sw = (((lane & 7) ^ (srow & 7)) << 3);      // swizzled col, shorts
    const int swr = ((m16 & 7) << 3);                     // read-side XOR, shorts

#pragma unroll
    for (int pass = 0; pass < 2; ++pass) {
        const int t = pass ? (31 - g) : g;        // 64-row tile index 0..31
        const int qbase = t * 64 + wv * 16;       // this wave's 16 q-rows

        short8 aq0 = *(const short8*)(Qp + (size_t)(qbase + m16) * 64 + quad * 8);
        short8 aq1 = *(const short8*)(Qp + (size_t)(qbase + m16) * 64 + 32 + quad * 8);

        f32x4 o[4];
#pragma unroll
        for (int dt = 0; dt < 4; ++dt) o[dt] = (f32x4){0.f, 0.f, 0.f, 0.f};
        float lrow[4] = {0.f, 0.f, 0.f, 0.f};

        for (int kt = 0; kt <= t; ++kt) {
            const int kb = kt << 6;

            // ---- stage K [64 key][64 d] and V^T [64 d][64 key] tiles ----
#pragma unroll
            for (int p = 0; p < 2; ++p) {
                const int c8 = wv * 2 + p;
                const int row = c8 * 8 + srow;
                gload_lds16(Kp + (size_t)(kb + row) * 64 + sw, ldsK + c8 * 512);
                gload_lds16(Vp + (size_t)row * 2048 + kb + sw, ldsV + c8 * 512);
            }
            __syncthreads();   // drains vmcnt(0): tiles complete

            // ---- QK^T: 4 key-blocks x 2 k-chunks ----
            f32x4 s[4];
#pragma unroll
            for (int c = 0; c < 4; ++c) {
                const short* kr = ldsK + (c * 16 + m16) * 64;
                short8 kf0 = *(const short8*)(kr + ((quad * 8) ^ swr));
                short8 kf1 = *(const short8*)(kr + ((quad * 8 + 32) ^ swr));
                f32x4 z = (f32x4){0.f, 0.f, 0.f, 0.f};
                z = MFMA16(aq0, kf0, z);
                z = MFMA16(aq1, kf1, z);
                s[c] = z;
            }

            // ---- exp + causal mask + P store (fixed-base; Q pre-scaled) ----
#pragma unroll
            for (int c = 0; c < 4; ++c) {
                const int key = kb + c * 16 + m16;
                const bool needmask = (kb + c * 16 + 15 > qbase);
#pragma unroll
                for (int r = 0; r < 4; ++r) {
                    float p = exp2f(s[c][r]);
                    if (needmask && key > qbase + quad * 4 + r) p = 0.f;
                    lrow[r] += p;
                    pw[(quad * 4 + r) * 72 + c * 16 + m16] = f2bf(p);
                }
            }

            // P (C-layout) -> A-operand via per-wave LDS round-trip
            asm volatile("" ::: "memory");
            short8 ap0 = *(const short8*)(pw + m16 * 72 + quad * 8);
            short8 ap1 = *(const short8*)(pw + m16 * 72 + quad * 8 + 32);
            asm volatile("" ::: "memory");

            // ---- PV: 4 d-blocks x 2 k-chunks ----
#pragma unroll
            for (int dt = 0; dt < 4; ++dt) {
                const short* vr = ldsV + (dt * 16 + m16) * 64;
                short8 vf0 = *(const short8*)(vr + ((quad * 8) ^ swr));
                short8 vf1 = *(const short8*)(vr + ((quad * 8 + 32) ^ swr));
                o[dt] = MFMA16(ap0, vf0, o[dt]);
                o[dt] = MFMA16(ap1, vf1, o[dt]);
            }
            __syncthreads();   // all reads done before next stage overwrites
        }

        // row-sum reduce over the 16 key-lanes (xor within m16 group)
        float linv[4];
#pragma unroll
        for (int r = 0; r < 4; ++r) {
            float sm = lrow[r];
#pragma unroll
            for (int off = 1; off < 16; off <<= 1)
                sm += __shfl_xor(sm, off);
            linv[r] = 1.0f / sm;
        }
#pragma unroll
        for (int dt = 0; dt < 4; ++dt) {
#pragma unroll
            for (int r = 0; r < 4; ++r) {
                int row = qbase + quad * 4 + r;
                int col = h * 64 + dt * 16 + m16;
                Y[((size_t)(b * 2048 + row)) * 1024 + col] = f2bf(o[dt][r] * linv[r]);
            }
        }
    }
}

// ---------------------------------------------------------------------------
extern "C" void kernel_launch(void* const* d_in, const int* in_sizes, int n_in,
                              void* d_out, int out_size, void* d_ws, size_t ws_size,
                              hipStream_t stream)
{
    const void* x      = d_in[0];
    const void* w_attn = d_in[1];
    const void* b_attn = d_in[2];
    const void* w_proj = d_in[3];
    const void* b_proj = d_in[4];

    char* ws = (char*)d_ws;
    unsigned int* flag = (unsigned int*)(ws + 0);
    short* Wta = (short*)(ws + 256);
    short* Wtp = (short*)(ws + 6291712);
    short* Qb  = (short*)(ws + 8388864);
    short* Kb  = (short*)(ws + 25166080);
    short* Vtb = (short*)(ws + 41943296);
    short* Yb  = (short*)(ws + 58720512);
    // Xb (bf16 x) REUSES the Yb slot: Xb's lifetime (cvt_x -> QKV gemm)
    // ends before Yb's begins (attn -> proj gemm); same stream, sequential.
    short* Xb  = (short*)(ws + 58720512);

    sniff_kernel<<<1, 256, 0, stream>>>((const unsigned int*)x, flag);
    cvt_x<<<dim3(4096), 256, 0, stream>>>(x, Xb, flag);
    transpose_cvt<<<dim3(48, 16), 256, 0, stream>>>(w_attn, Wta, 1024, 3072, flag);
    transpose_cvt<<<dim3(16, 16), 256, 0, stream>>>(w_proj, Wtp, 1024, 1024, flag);
    gemm_kernel<1><<<dim3(24, 64), 256, 0, stream>>>(Xb, Wta, b_attn, Qb, Kb, Vtb,
                                                     8192, 3072, 1024, flag);
    attn_kernel<<<dim3(1024), 256, 0, stream>>>(Qb, Kb, Vtb, Yb);
    gemm_kernel<0><<<dim3(8, 64), 256, 0, stream>>>(Yb, Wtp, b_proj, d_out, nullptr, nullptr,
                                                    8192, 1024, 1024, flag);
}